// Round 9
// baseline (338.096 us; speedup 1.0000x reference)
//
#include <hip/hip_runtime.h>
#include <hip/hip_bf16.h>
#include <stdint.h>

// ExpanderLinear: y[t,o] = sum_i x[t,i] * (w[o,i]*mask[o,i]) + bias[o]
// M=8192, K=4096, N=4096. f32 in/out, bf16 MFMA compute.
// R9: 4-wave kernel, 256x256 block tile, per-wave 128x128 output (2x LDS
// amplification instead of 3x). LDS ring-5 of BK=32 units (160 KiB exactly).
// Register double-buffer: MFMA cluster (64) runs on last iter's operands
// while this iter's 16 ds_reads + 8 global_load_lds are serviced.
// Counted vmcnt(16) at iter top (retires only 3-iter-old batches, no stall).

typedef __attribute__((ext_vector_type(4))) float          f32x4;
typedef __attribute__((ext_vector_type(4))) int            i32x4;
typedef __attribute__((ext_vector_type(4))) unsigned short u16x4;
typedef __attribute__((ext_vector_type(8))) __bf16         bf16x8;

static constexpr int M = 8192;
static constexpr int N = 4096;
static constexpr int K = 4096;
static constexpr int NU = K / 32;       // 128 half-K units

#define GLOBAL_AS(p) ((const __attribute__((address_space(1))) void*)(p))
#define LDS_AS(p)    ((__attribute__((address_space(3))) void*)(p))

__device__ __forceinline__ unsigned short f2bf(float f) {
    unsigned int u = __float_as_uint(f);
    u = (u + 0x7fffu + ((u >> 16) & 1u)) >> 16;
    return (unsigned short)u;
}

// ---- prep 1: x f32 -> bf16 ----
__global__ void cvt_x_kernel(const float* __restrict__ x,
                             unsigned short* __restrict__ out) {
    int i = blockIdx.x * blockDim.x + threadIdx.x;
    f32x4 v = ((const f32x4*)x)[i];
    u16x4 r;
    r.x = f2bf(v.x); r.y = f2bf(v.y); r.z = f2bf(v.z); r.w = f2bf(v.w);
    ((u16x4*)out)[i] = r;
}

// ---- prep 2: (w * mask) f32 -> bf16, fused ----
__global__ void cvt_wm_kernel(const float* __restrict__ w,
                              const int* __restrict__ mask,
                              unsigned short* __restrict__ out) {
    int i = blockIdx.x * blockDim.x + threadIdx.x;
    f32x4 v = ((const f32x4*)w)[i];
    i32x4 m = ((const i32x4*)mask)[i];
    u16x4 r;
    r.x = m.x ? f2bf(v.x) : (unsigned short)0;
    r.y = m.y ? f2bf(v.y) : (unsigned short)0;
    r.z = m.z ? f2bf(v.z) : (unsigned short)0;
    r.w = m.w ? f2bf(v.w) : (unsigned short)0;
    ((u16x4*)out)[i] = r;
}

// ---- main GEMM ----
// LDS: ring-5 units of 32 KiB: A [256 rows][32 bf16] (16KB) + B same (16KB).
// Unit u lives in slot u % 5. Iter u: MFMA on unit-u regs (read at iter u-1),
// ds_read unit u+1 -> other reg buffer, stage unit u+4 (staged 4 ahead;
// slot (u+4)%5 == (u-1)%5, whose reads were consumed at iter u-1 -> the
// iter-u top barrier separates them: race-free).
// Swizzle (within 128B row-pair): phys3 = (((row&1)<<2)|fq) ^ ((row>>1)&7).
// LDS writes stay linear (global_load_lds); global SOURCE pre-swizzled.
__global__ void __launch_bounds__(256, 1)
gemm4_bf16(const unsigned short* __restrict__ A,   // [M][K] bf16 bits
           const unsigned short* __restrict__ B,   // [N][K] bf16 bits
           const float* __restrict__ bias,         // [N]
           float* __restrict__ C) {                // [M][N] f32
    extern __shared__ unsigned short lds[];        // 5 * 16384 elems

    const int tid  = threadIdx.x;
    const int lane = tid & 63;
    const int wave = tid >> 6;                     // 0..3

    // T1: XCD-aware bijective swizzle (nwg = 512, % 8 == 0)
    const int bid = blockIdx.x;
    const int swz = (bid & 7) * 64 + (bid >> 3);
    const int brow = (swz >> 4) * 256;             // ntn = 16
    const int bcol = (swz & 15) * 256;

    const int wrow = (wave >> 1) * 128;            // wave output rows
    const int wcol = (wave & 1) * 128;             // wave output cols
    const int fr = lane & 15;                      // fragment row/col
    const int fq = lane >> 4;                      // k-subgroup

    // read-side swizzle bases (byte offsets within a 32KB slot)
    const int s3r   = (((fr & 1) << 2) | fq) ^ (fr >> 1);
    const int abase = wrow * 64 + (fr >> 1) * 128 + s3r * 16;           // A region
    const int bbase = 16384 + wcol * 64 + (fr >> 1) * 128 + s3r * 16;   // B region

    // write-side: lane's linear LDS slot -> logical (row, col) in global
    const int l8 = lane & 7, lh = lane >> 3;
    const int s3w    = l8 ^ lh;
    const int wrow_l = 2 * lh + (s3w >> 2);        // row within 16-row chunk
    const int wcol_l = (s3w & 3) * 8;              // bf16 col within 32-col unit

    const unsigned short* __restrict__ Ag = A + (size_t)brow * K;
    const unsigned short* __restrict__ Bg = B + (size_t)bcol * K;

    f32x4 acc[8][8];
#pragma unroll
    for (int m = 0; m < 8; ++m)
#pragma unroll
        for (int n = 0; n < 8; ++n) acc[m][n] = (f32x4)(0.0f);

    // double-buffered operand registers (static names, rule #20)
    bf16x8 pa0[8], pb0[8], pa1[8], pb1[8];

#define STG1(dst, src) __builtin_amdgcn_global_load_lds(GLOBAL_AS(src), LDS_AS(dst), 16, 0, 0)
// stage unit j (A 16KB + B 16KB) into slot s: 8 gloads/thread
#define STAGE(s, j) do {                                                        \
    _Pragma("unroll")                                                           \
    for (int c = 0; c < 4; ++c) {                                               \
        const int q_ = c * 4 + wave;                                            \
        STG1(lds + (s) * 16384 + q_ * 512,                                      \
             Ag + (size_t)(q_ * 16 + wrow_l) * K + (j) * 32 + wcol_l);          \
        STG1(lds + (s) * 16384 + 8192 + q_ * 512,                               \
             Bg + (size_t)(q_ * 16 + wrow_l) * K + (j) * 32 + wcol_l);          \
    }                                                                           \
  } while (0)
// read unit in slot s into (pa, pb): 16 ds_read_b128
#define LDAB(pa, pb, s) do {                                                    \
    const char* base_ = (const char*)lds + (s) * 32768;                         \
    _Pragma("unroll")                                                           \
    for (int m = 0; m < 8; ++m)                                                 \
        pa[m] = *(const bf16x8*)(base_ + abase + m * 1024);                     \
    _Pragma("unroll")                                                           \
    for (int n = 0; n < 8; ++n)                                                 \
        pb[n] = *(const bf16x8*)(base_ + bbase + n * 1024);                     \
  } while (0)
#define MM64(pa, pb) do {                                                       \
    __builtin_amdgcn_s_setprio(1);                                              \
    _Pragma("unroll")                                                           \
    for (int m = 0; m < 8; ++m)                                                 \
      _Pragma("unroll")                                                         \
      for (int n = 0; n < 8; ++n)                                               \
        acc[m][n] = __builtin_amdgcn_mfma_f32_16x16x32_bf16(                    \
            pa[m], pb[n], acc[m][n], 0, 0, 0);                                  \
    __builtin_amdgcn_s_setprio(0);                                              \
  } while (0)
#define BAR    __builtin_amdgcn_s_barrier()
#define FENCE  asm volatile("" ::: "memory")
#define SCHED0 __builtin_amdgcn_sched_barrier(0)
#define WVM(n) asm volatile("s_waitcnt vmcnt(" #n ")" ::: "memory")

    // prologue: stage units 0-3 (slots 0-3), retire unit 0, preload its regs
    STAGE(0, 0); STAGE(1, 1); STAGE(2, 2); STAGE(3, 3);
    WVM(24);            // 32 outstanding -> 24: unit 0 resident
    BAR; FENCE;
    LDAB(pa0, pb0, 0);

    // main loop: iters u = 0..123 as 62 pairs. Iter u: WVM(16) retires unit
    // u+1 (staged at iter u-3, aged ~3000 cyc); stage unit u+4; read unit u+1;
    // MFMA on unit u. Slots advance +2 mod 5 per pair.
    int s1 = 1, s2 = 2, s4 = 4, s5 = 0;
#pragma unroll 1
    for (int u = 0; u < 124; u += 2) {
        // iter u (even): compute unit u from pa0/pb0
        WVM(16); BAR; FENCE;
        STAGE(s4, u + 4);
        LDAB(pa1, pb1, s1);
        SCHED0;
        MM64(pa0, pb0);
        // iter u+1 (odd): compute unit u+1 from pa1/pb1
        WVM(16); BAR; FENCE;
        STAGE(s5, u + 5);
        LDAB(pa0, pb0, s2);
        SCHED0;
        MM64(pa1, pb1);
        s1 += 2; if (s1 >= 5) s1 -= 5;
        s2 += 2; if (s2 >= 5) s2 -= 5;
        s4 += 2; if (s4 >= 5) s4 -= 5;
        s5 += 2; if (s5 >= 5) s5 -= 5;
    }
    // tail: u = 124..127 (no staging; units 125,126,127 in slots 0,1,2)
    WVM(16); BAR; FENCE; LDAB(pa1, pb1, 0); SCHED0; MM64(pa0, pb0);  // u=124
    WVM(8);  BAR; FENCE; LDAB(pa0, pb0, 1); SCHED0; MM64(pa1, pb1);  // u=125
    WVM(0);  BAR; FENCE; LDAB(pa1, pb1, 2); SCHED0; MM64(pa0, pb0);  // u=126
    MM64(pa1, pb1);                                                  // u=127

    // epilogue: C/D layout col=lane&15, row=(lane>>4)*4+reg [m89/m91]
    float bv[8];
#pragma unroll
    for (int n = 0; n < 8; ++n) bv[n] = bias[bcol + wcol + n * 16 + fr];
#pragma unroll
    for (int m = 0; m < 8; ++m) {
#pragma unroll
        for (int j = 0; j < 4; ++j) {
            const int row = brow + wrow + m * 16 + fq * 4 + j;
            float* crow = C + (size_t)row * N + bcol + wcol + fr;
#pragma unroll
            for (int n = 0; n < 8; ++n) crow[n * 16] = acc[m][n][j] + bv[n];
        }
    }
#undef STG1
#undef STAGE
#undef LDAB
#undef MM64
#undef BAR
#undef FENCE
#undef SCHED0
#undef WVM
}

// ---- fallback (only if ws too small): f32 vector GEMM ----
__global__ void fallback_gemm(const float* __restrict__ x,
                              const float* __restrict__ w,
                              const int* __restrict__ mask,
                              const float* __restrict__ bias,
                              float* __restrict__ C) {
    const int tid = threadIdx.x;
    const int tx = tid & 15, ty = tid >> 4;
    const int brow = blockIdx.y * 64, bcol = blockIdx.x * 64;
    __shared__ float As[64][17];
    __shared__ float Ws[64][17];
    float acc[4][4] = {};
    for (int k0 = 0; k0 < K; k0 += 16) {
        __syncthreads();
        for (int i = tid; i < 64 * 16; i += 256) {
            int r = i >> 4, c = i & 15;
            As[r][c] = x[(size_t)(brow + r) * K + k0 + c];
            float wv = w[(size_t)(bcol + r) * K + k0 + c];
            Ws[r][c] = mask[(size_t)(bcol + r) * K + k0 + c] ? wv : 0.0f;
        }
        __syncthreads();
        for (int kk = 0; kk < 16; ++kk) {
            float a[4], b[4];
#pragma unroll
            for (int i = 0; i < 4; ++i) a[i] = As[ty * 4 + i][kk];
#pragma unroll
            for (int i = 0; i < 4; ++i) b[i] = Ws[tx * 4 + i][kk];
#pragma unroll
            for (int i = 0; i < 4; ++i)
#pragma unroll
                for (int j = 0; j < 4; ++j) acc[i][j] += a[i] * b[j];
        }
    }
    for (int i = 0; i < 4; ++i)
        for (int j = 0; j < 4; ++j) {
            int row = brow + ty * 4 + i, col = bcol + tx * 4 + j;
            C[(size_t)row * N + col] = acc[i][j] + bias[col];
        }
}

extern "C" void kernel_launch(void* const* d_in, const int* in_sizes, int n_in,
                              void* d_out, int out_size, void* d_ws, size_t ws_size,
                              hipStream_t stream) {
    const float* x    = (const float*)d_in[0];
    const float* w    = (const float*)d_in[1];
    const float* bias = (const float*)d_in[2];
    const int*   mask = (const int*)d_in[3];
    float* out = (float*)d_out;

    const size_t need = ((size_t)M * K + (size_t)N * K) * sizeof(unsigned short);
    if (ws_size >= need) {
        unsigned short* xb = (unsigned short*)d_ws;           // [M][K] bf16
        unsigned short* wb = xb + (size_t)M * K;              // [N][K] bf16
        (void)hipFuncSetAttribute((const void*)gemm4_bf16,
                                  hipFuncAttributeMaxDynamicSharedMemorySize,
                                  163840);
        cvt_x_kernel<<<(M * K / 4) / 256, 256, 0, stream>>>(x, xb);
        cvt_wm_kernel<<<(N * K / 4) / 256, 256, 0, stream>>>(w, mask, wb);
        gemm4_bf16<<<(M / 256) * (N / 256), 256, 163840, stream>>>(xb, wb, bias, out);
    } else {
        dim3 g(N / 64, M / 64);
        fallback_gemm<<<g, 256, 0, stream>>>(x, w, mask, bias, out);
    }
}